// Round 9
// baseline (82.157 us; speedup 1.0000x reference)
//
#include <hip/hip_runtime.h>

#define N_NODES 5000
#define N_EDGES 40000
#define ROWS 48            // BATCH * SEQ = 4*12
#define FIN 64
#define FOUT 64
#define NODE_ELEMS (ROWS * FIN)     // 3072
#define OUT_ROW 128                 // concat(FOUT, FOUT)
#define NODE_OUT (ROWS * OUT_ROW)   // 6144
#define CAP 64                      // per-node edge bucket capacity (max degree ~25)
#define M_ROWS (N_NODES * ROWS)     // 240000 global rows

typedef float f32x4 __attribute__((ext_vector_type(4)));
typedef short bf16x8 __attribute__((ext_vector_type(8)));

__device__ __forceinline__ unsigned short f32_to_bf16_rne(float f) {
    unsigned int u = __float_as_uint(f);
    u += 0x7fffu + ((u >> 16) & 1u);
    return (unsigned short)(u >> 16);
}

// ---------------- prep: zero counts (blocks 0..19) + build Wt bf16 (block 20) ----------------
// Wt[j][k] = bf16(W[k][j]) : 64x64 bf16, row-major in j (so a B-column fragment is contiguous)

__global__ void prep_kernel(const float* __restrict__ W,
                            int* __restrict__ counts,
                            unsigned short* __restrict__ Wt) {
    const int tid = threadIdx.x;
    if (blockIdx.x < 20) {
        int i = blockIdx.x * 256 + tid;
        if (i < N_NODES) counts[i] = 0;
    } else {
        // 4096 elems, 16 per thread: idx = tid*16 + m -> j = idx>>6, k = idx&63
        int base = tid * 16;
        int j = base >> 6;
        int k0 = base & 63;
        ushort4 pk[4];
        #pragma unroll
        for (int q = 0; q < 4; ++q) {
            unsigned short p[4];
            #pragma unroll
            for (int m = 0; m < 4; ++m)
                p[m] = f32_to_bf16_rne(W[(k0 + q * 4 + m) * 64 + j]);
            pk[q].x = p[0]; pk[q].y = p[1]; pk[q].z = p[2]; pk[q].w = p[3];
        }
        #pragma unroll
        for (int q = 0; q < 4; ++q)
            *(ushort4*)(Wt + j * 64 + k0 + q * 4) = pk[q];
    }
}

__global__ void bucket_kernel(const int* __restrict__ edges_dst,
                              const int* __restrict__ edges_src,
                              int* __restrict__ counts,
                              int* __restrict__ bucket) {
    int e = blockIdx.x * 256 + threadIdx.x;
    if (e < N_EDGES) {
        int d = edges_dst[e];
        int slot = atomicAdd(&counts[d], 1);
        if (slot < CAP) bucket[d * CAP + slot] = edges_src[e];
    }
}

// ---------------- Kernel 1: MFMA GEMM  left = relu(F@W), Q = bf16(F@W) ----------------
// Block = 64 rows, 4 waves x (16 rows x 64 cols). A direct-from-global; B from Wt;
// epilogue transposed through LDS for fully-coalesced vector stores.

__global__ __launch_bounds__(256) void mfma_matmul_kernel(
    const float* __restrict__ feat,          // [M_ROWS][64]
    const unsigned short* __restrict__ Wt,   // [64 cols][64 k] bf16
    float* __restrict__ out,                 // [M_ROWS][128] (left half)
    unsigned short* __restrict__ Q) {        // [M_ROWS][64] bf16
    __shared__ __align__(16) float c_lds[64 * 64];   // 16 KB epilogue transpose

    const int tid  = threadIdx.x;
    const int wave = tid >> 6;
    const int lane = tid & 63;
    const int row16 = lane & 15;   // A-row within tile; C-col within 16
    const int koct  = lane >> 4;   // 0..3

    const size_t g0 = (size_t)blockIdx.x * 64;

    // ---- A fragments direct from global: a[s][m] = feat[row][s*32 + koct*8 + m] ----
    const float* arow = feat + (g0 + wave * 16 + row16) * FIN + koct * 8;
    f32x4 a00 = *(const f32x4*)(arow);            // k: koct*8 + 0..3
    f32x4 a01 = *(const f32x4*)(arow + 4);        // k: koct*8 + 4..7
    f32x4 a10 = *(const f32x4*)(arow + 32);       // k: 32 + koct*8 + 0..3
    f32x4 a11 = *(const f32x4*)(arow + 36);

    // ---- B fragments from Wt: one 16B load per (s,t) ----
    bf16x8 bfrag[2][4];
    #pragma unroll
    for (int t = 0; t < 4; ++t) {
        const unsigned short* wcol = Wt + (t * 16 + row16) * 64 + koct * 8;
        bfrag[0][t] = *(const bf16x8*)(wcol);
        bfrag[1][t] = *(const bf16x8*)(wcol + 32);
    }

    bf16x8 afrag[2];
    {
        unsigned short p[16];
        #pragma unroll
        for (int m = 0; m < 4; ++m) {
            p[m]      = f32_to_bf16_rne(a00[m]);
            p[4 + m]  = f32_to_bf16_rne(a01[m]);
            p[8 + m]  = f32_to_bf16_rne(a10[m]);
            p[12 + m] = f32_to_bf16_rne(a11[m]);
        }
        #pragma unroll
        for (int m = 0; m < 8; ++m) { afrag[0][m] = (short)p[m]; afrag[1][m] = (short)p[8 + m]; }
    }

    f32x4 acc[4];
    #pragma unroll
    for (int t = 0; t < 4; ++t) acc[t] = (f32x4){0.f, 0.f, 0.f, 0.f};

    #pragma unroll
    for (int s = 0; s < 2; ++s)
        #pragma unroll
        for (int t = 0; t < 4; ++t)
            acc[t] = __builtin_amdgcn_mfma_f32_16x16x32_bf16(afrag[s], bfrag[s][t], acc[t], 0, 0, 0);

    // ---- transpose: C[row_local = wave*16 + koct*4 + p][col = t*16 + row16] ----
    #pragma unroll
    for (int t = 0; t < 4; ++t)
        #pragma unroll
        for (int p = 0; p < 4; ++p)
            c_lds[(wave * 16 + koct * 4 + p) * 64 + t * 16 + row16] = acc[t][p];
    __syncthreads();

    // ---- coalesced stores: left half (relu) ----
    #pragma unroll
    for (int i = 0; i < 4; ++i) {
        int c = tid + i * 256;          // f32x4 chunk id, 0..1023
        int r = c >> 4;
        int cq = c & 15;
        f32x4 v = ((const f32x4*)c_lds)[c];
        f32x4 rv = {fmaxf(v.x, 0.f), fmaxf(v.y, 0.f), fmaxf(v.z, 0.f), fmaxf(v.w, 0.f)};
        *(f32x4*)(out + (g0 + r) * OUT_ROW + cq * 4) = rv;
    }
    // ---- coalesced Q stores (raw, bf16) ----
    #pragma unroll
    for (int i = 0; i < 2; ++i) {
        int c = tid + i * 256;          // 8-elem chunk id, 0..511
        int r = c >> 3;
        int part = c & 7;
        const float* src = c_lds + r * 64 + part * 8;
        ushort4 lo, hi;
        lo.x = f32_to_bf16_rne(src[0]); lo.y = f32_to_bf16_rne(src[1]);
        lo.z = f32_to_bf16_rne(src[2]); lo.w = f32_to_bf16_rne(src[3]);
        hi.x = f32_to_bf16_rne(src[4]); hi.y = f32_to_bf16_rne(src[5]);
        hi.z = f32_to_bf16_rne(src[6]); hi.w = f32_to_bf16_rne(src[7]);
        unsigned short* dst = Q + (g0 + r) * FIN + part * 8;
        *(ushort4*)(dst) = lo;
        *(ushort4*)(dst + 4) = hi;
    }
}

// ---------------- Kernel 2: right half = relu(mean_src Q_bf16[src]) ----------------

__device__ __forceinline__ void acc_u4(float* a, uint4 v) {
    a[0] += __uint_as_float(v.x << 16); a[1] += __uint_as_float(v.x & 0xffff0000u);
    a[2] += __uint_as_float(v.y << 16); a[3] += __uint_as_float(v.y & 0xffff0000u);
    a[4] += __uint_as_float(v.z << 16); a[5] += __uint_as_float(v.z & 0xffff0000u);
    a[6] += __uint_as_float(v.w << 16); a[7] += __uint_as_float(v.w & 0xffff0000u);
}

__global__ __launch_bounds__(384) void gather_kernel(
    const unsigned short* __restrict__ Q,
    const int* __restrict__ counts,
    const int* __restrict__ bucket,
    float* __restrict__ out) {
    const int n = blockIdx.x;
    const int tid = threadIdx.x;
    const int cnt_true = counts[n];
    const int cnt = cnt_true < CAP ? cnt_true : CAP;
    const int* bk = bucket + n * CAP;

    float acc[8];
    #pragma unroll
    for (int i = 0; i < 8; ++i) acc[i] = 0.f;

    int e = 0;
    for (; e + 4 <= cnt; e += 4) {
        const unsigned short* q0 = Q + (size_t)bk[e]     * NODE_ELEMS;
        const unsigned short* q1 = Q + (size_t)bk[e + 1] * NODE_ELEMS;
        const unsigned short* q2 = Q + (size_t)bk[e + 2] * NODE_ELEMS;
        const unsigned short* q3 = Q + (size_t)bk[e + 3] * NODE_ELEMS;
        uint4 a0 = *(const uint4*)(q0 + tid * 8);
        uint4 a1 = *(const uint4*)(q1 + tid * 8);
        uint4 a2 = *(const uint4*)(q2 + tid * 8);
        uint4 a3 = *(const uint4*)(q3 + tid * 8);
        acc_u4(acc, a0); acc_u4(acc, a1); acc_u4(acc, a2); acc_u4(acc, a3);
    }
    for (; e < cnt; ++e) {
        const unsigned short* q0 = Q + (size_t)bk[e] * NODE_ELEMS;
        uint4 a0 = *(const uint4*)(q0 + tid * 8);
        acc_u4(acc, a0);
    }

    const float inv = 1.0f / (float)(cnt_true > 1 ? cnt_true : 1);
    float* outn = out + (size_t)n * NODE_OUT;

    int r = tid >> 3, c = (tid & 7) * 8;
    float* p = outn + r * OUT_ROW + 64 + c;
    f32x4 v0 = {fmaxf(acc[0] * inv, 0.f), fmaxf(acc[1] * inv, 0.f),
                fmaxf(acc[2] * inv, 0.f), fmaxf(acc[3] * inv, 0.f)};
    f32x4 v1 = {fmaxf(acc[4] * inv, 0.f), fmaxf(acc[5] * inv, 0.f),
                fmaxf(acc[6] * inv, 0.f), fmaxf(acc[7] * inv, 0.f)};
    *(f32x4*)(p)     = v0;
    *(f32x4*)(p + 4) = v1;
}

// ---------------- Fallback path (tiny ws): scan CSR + fused f32 kernel ----------------

__global__ void zero_counts_kernel(int* __restrict__ counts) {
    int i = blockIdx.x * 256 + threadIdx.x;
    if (i < N_NODES) counts[i] = 0;
}

__global__ void hist_kernel(const int* __restrict__ edges_dst, int* __restrict__ counts) {
    int e = blockIdx.x * 256 + threadIdx.x;
    if (e < N_EDGES) atomicAdd(&counts[edges_dst[e]], 1);
}

__global__ void scan_kernel(const int* __restrict__ counts,
                            int* __restrict__ offsets,
                            int* __restrict__ cursor) {
    __shared__ int buf[1024];
    __shared__ int carry_s;
    int tid = threadIdx.x;
    if (tid == 0) carry_s = 0;
    __syncthreads();
    for (int base = 0; base < N_NODES; base += 1024) {
        int i = base + tid;
        int v = (i < N_NODES) ? counts[i] : 0;
        buf[tid] = v;
        __syncthreads();
        int x = v;
        for (int off = 1; off < 1024; off <<= 1) {
            int t = (tid >= off) ? buf[tid - off] : 0;
            __syncthreads();
            x += t;
            buf[tid] = x;
            __syncthreads();
        }
        int c = carry_s;
        if (i < N_NODES) {
            int excl = c + x - v;
            offsets[i] = excl;
            cursor[i] = excl;
        }
        __syncthreads();
        if (tid == 0) carry_s = c + buf[1023];
        __syncthreads();
    }
    if (threadIdx.x == 0) offsets[N_NODES] = carry_s;
}

__global__ void scatter_kernel(const int* __restrict__ edges_dst,
                               const int* __restrict__ edges_src,
                               int* __restrict__ cursor,
                               int* __restrict__ csr_src) {
    int e = blockIdx.x * 256 + threadIdx.x;
    if (e < N_EDGES) {
        int d = edges_dst[e];
        int p = atomicAdd(&cursor[d], 1);
        csr_src[p] = edges_src[e];
    }
}

__global__ __launch_bounds__(256) void fused_kernel(
    const float* __restrict__ feat,
    const float* __restrict__ W,
    const int* __restrict__ offsets,
    const int* __restrict__ csr_src,
    float* __restrict__ out) {
    __shared__ __align__(16) float lds_w[FIN * FOUT];
    __shared__ __align__(16) float lds_t[NODE_ELEMS];

    const int n = blockIdx.x;
    const int tid = threadIdx.x;

    {
        const f32x4* w4 = (const f32x4*)W;
        f32x4* l4 = (f32x4*)lds_w;
        #pragma unroll
        for (int i = 0; i < 4; ++i) l4[tid + i * 256] = w4[tid + i * 256];
    }
    {
        const f32x4* f4 = (const f32x4*)(feat + (size_t)n * NODE_ELEMS);
        f32x4* l4 = (f32x4*)lds_t;
        #pragma unroll
        for (int i = 0; i < 3; ++i) l4[tid + i * 256] = f4[tid + i * 256];
    }
    __syncthreads();

    const int j = tid & 63;
    float wcol[64];
    #pragma unroll
    for (int k = 0; k < 64; ++k) wcol[k] = lds_w[k * 64 + j];

    float* outn = out + (size_t)n * NODE_OUT;

    #pragma unroll
    for (int i = 0; i < 12; ++i) {
        int r = (tid + i * 256) >> 6;
        const f32x4* m4 = (const f32x4*)(lds_t + r * 64);
        float s = 0.f;
        #pragma unroll
        for (int k4 = 0; k4 < 16; ++k4) {
            f32x4 m = m4[k4];
            s += m.x * wcol[4 * k4 + 0] + m.y * wcol[4 * k4 + 1] +
                 m.z * wcol[4 * k4 + 2] + m.w * wcol[4 * k4 + 3];
        }
        outn[r * OUT_ROW + j] = fmaxf(s, 0.f);
    }

    const int e0 = offsets[n], e1 = offsets[n + 1];
    f32x4 acc[3];
    #pragma unroll
    for (int i = 0; i < 3; ++i) acc[i] = (f32x4){0.f, 0.f, 0.f, 0.f};
    for (int e = e0; e < e1; ++e) {
        int src = csr_src[e];
        const f32x4* f4 = (const f32x4*)(feat + (size_t)src * NODE_ELEMS);
        #pragma unroll
        for (int i = 0; i < 3; ++i) acc[i] += f4[tid + i * 256];
    }
    const float inv = 1.0f / (float)((e1 - e0) > 1 ? (e1 - e0) : 1);

    __syncthreads();
    {
        f32x4* l4 = (f32x4*)lds_t;
        #pragma unroll
        for (int i = 0; i < 3; ++i) l4[tid + i * 256] = acc[i] * inv;
    }
    __syncthreads();

    #pragma unroll
    for (int i = 0; i < 12; ++i) {
        int r = (tid + i * 256) >> 6;
        const f32x4* m4 = (const f32x4*)(lds_t + r * 64);
        float s = 0.f;
        #pragma unroll
        for (int k4 = 0; k4 < 16; ++k4) {
            f32x4 m = m4[k4];
            s += m.x * wcol[4 * k4 + 0] + m.y * wcol[4 * k4 + 1] +
                 m.z * wcol[4 * k4 + 2] + m.w * wcol[4 * k4 + 3];
        }
        outn[r * OUT_ROW + 64 + j] = fmaxf(s, 0.f);
    }
}

// ---------------- launch ----------------

extern "C" void kernel_launch(void* const* d_in, const int* in_sizes, int n_in,
                              void* d_out, int out_size, void* d_ws, size_t ws_size,
                              hipStream_t stream) {
    const float* feat = (const float*)d_in[0];
    const float* W    = (const float*)d_in[1];
    const int* edst   = (const int*)d_in[2];
    const int* esrc   = (const int*)d_in[3];
    float* out = (float*)d_out;

    // bucket-path layout
    int* counts  = (int*)d_ws;                               // 5000 ints (pad to 20480 B)
    int* bucket  = (int*)((char*)d_ws + 20480);              // 5000*64 ints = 1.28 MB
    const size_t wt_off = 20480 + (size_t)N_NODES * CAP * 4; // 1,300,480
    unsigned short* Wt = (unsigned short*)((char*)d_ws + wt_off);   // 8 KB
    const size_t q_off = wt_off + 8192;                      // 1,308,672 (256-aligned)
    unsigned short* Q = (unsigned short*)((char*)d_ws + q_off);
    const size_t q_bytes = (size_t)N_NODES * NODE_ELEMS * 2; // 30.72 MB

    if (ws_size >= q_off + q_bytes) {
        prep_kernel<<<21, 256, 0, stream>>>(W, counts, Wt);
        bucket_kernel<<<(N_EDGES + 255) / 256, 256, 0, stream>>>(edst, esrc, counts, bucket);
        mfma_matmul_kernel<<<M_ROWS / 64, 256, 0, stream>>>(feat, Wt, out, Q);
        gather_kernel<<<N_NODES, 384, 0, stream>>>(Q, counts, bucket, out);
    } else {
        // fallback: packed CSR + fused f32 kernel (tiny ws)
        int* offsets = counts + N_NODES;
        int* cursor  = offsets + N_NODES + 1;
        int* csr_src = cursor + N_NODES;
        zero_counts_kernel<<<(N_NODES + 255) / 256, 256, 0, stream>>>(counts);
        hist_kernel<<<(N_EDGES + 255) / 256, 256, 0, stream>>>(edst, counts);
        scan_kernel<<<1, 1024, 0, stream>>>(counts, offsets, cursor);
        scatter_kernel<<<(N_EDGES + 255) / 256, 256, 0, stream>>>(edst, esrc, cursor, csr_src);
        fused_kernel<<<N_NODES, 256, 0, stream>>>(feat, W, offsets, csr_src, out);
    }
}

// Round 10
// 78.560 us; speedup vs baseline: 1.0458x; 1.0458x over previous
//
#include <hip/hip_runtime.h>

#define N_NODES 5000
#define N_EDGES 40000
#define ROWS 48            // BATCH * SEQ = 4*12
#define FIN 64
#define FOUT 64
#define NODE_ELEMS (ROWS * FIN)     // 3072
#define OUT_ROW 128                 // concat(FOUT, FOUT)
#define NODE_OUT (ROWS * OUT_ROW)   // 6144
#define CAP 64                      // per-node edge bucket capacity (max degree ~25)
#define M_ROWS (N_NODES * ROWS)     // 240000 global rows
#define EDGE_BLOCKS ((N_EDGES + 255) / 256)   // 157

typedef float f32x4 __attribute__((ext_vector_type(4)));
typedef short bf16x8 __attribute__((ext_vector_type(8)));

__device__ __forceinline__ unsigned short f32_to_bf16_rne(float f) {
    unsigned int u = __float_as_uint(f);
    u += 0x7fffu + ((u >> 16) & 1u);
    return (unsigned short)(u >> 16);
}

// ---------------- bucket CSR + Wt build (one launch; counts pre-zeroed by memset) ----------------
// Wt[j][k] = bf16(W[k][j])

__global__ void bucket_wt_kernel(const int* __restrict__ edges_dst,
                                 const int* __restrict__ edges_src,
                                 const float* __restrict__ W,
                                 int* __restrict__ counts,
                                 int* __restrict__ bucket,
                                 unsigned short* __restrict__ Wt) {
    const int tid = threadIdx.x;
    if (blockIdx.x < EDGE_BLOCKS) {
        int e = blockIdx.x * 256 + tid;
        if (e < N_EDGES) {
            int d = edges_dst[e];
            int slot = atomicAdd(&counts[d], 1);
            if (slot < CAP) bucket[d * CAP + slot] = edges_src[e];
        }
    } else {
        // 4096 elems, 16 per thread: j = col, k = row of W
        int base = tid * 16;
        int j = base >> 6;
        int k0 = base & 63;
        #pragma unroll
        for (int q = 0; q < 4; ++q) {
            ushort4 pk;
            pk.x = f32_to_bf16_rne(W[(k0 + q * 4 + 0) * 64 + j]);
            pk.y = f32_to_bf16_rne(W[(k0 + q * 4 + 1) * 64 + j]);
            pk.z = f32_to_bf16_rne(W[(k0 + q * 4 + 2) * 64 + j]);
            pk.w = f32_to_bf16_rne(W[(k0 + q * 4 + 3) * 64 + j]);
            *(ushort4*)(Wt + j * 64 + k0 + q * 4) = pk;
        }
    }
}

// ---------------- Kernel 1: MFMA GEMM  left = relu(F@W), Q = bf16(F@W) ----------------
// Block = 64 rows, 4 waves x (16 rows x 64 cols). A direct-from-global; B from Wt;
// epilogue transposed through LDS for fully-coalesced vector stores. (R9-proven)

__global__ __launch_bounds__(256) void mfma_matmul_kernel(
    const float* __restrict__ feat,          // [M_ROWS][64]
    const unsigned short* __restrict__ Wt,   // [64 cols][64 k] bf16
    float* __restrict__ out,                 // [M_ROWS][128] (left half)
    unsigned short* __restrict__ Q) {        // [M_ROWS][64] bf16
    __shared__ __align__(16) float c_lds[64 * 64];   // 16 KB epilogue transpose

    const int tid  = threadIdx.x;
    const int wave = tid >> 6;
    const int lane = tid & 63;
    const int row16 = lane & 15;
    const int koct  = lane >> 4;

    const size_t g0 = (size_t)blockIdx.x * 64;

    const float* arow = feat + (g0 + wave * 16 + row16) * FIN + koct * 8;
    f32x4 a00 = *(const f32x4*)(arow);
    f32x4 a01 = *(const f32x4*)(arow + 4);
    f32x4 a10 = *(const f32x4*)(arow + 32);
    f32x4 a11 = *(const f32x4*)(arow + 36);

    bf16x8 bfrag[2][4];
    #pragma unroll
    for (int t = 0; t < 4; ++t) {
        const unsigned short* wcol = Wt + (t * 16 + row16) * 64 + koct * 8;
        bfrag[0][t] = *(const bf16x8*)(wcol);
        bfrag[1][t] = *(const bf16x8*)(wcol + 32);
    }

    bf16x8 afrag[2];
    {
        unsigned short p[16];
        #pragma unroll
        for (int m = 0; m < 4; ++m) {
            p[m]      = f32_to_bf16_rne(a00[m]);
            p[4 + m]  = f32_to_bf16_rne(a01[m]);
            p[8 + m]  = f32_to_bf16_rne(a10[m]);
            p[12 + m] = f32_to_bf16_rne(a11[m]);
        }
        #pragma unroll
        for (int m = 0; m < 8; ++m) { afrag[0][m] = (short)p[m]; afrag[1][m] = (short)p[8 + m]; }
    }

    f32x4 acc[4];
    #pragma unroll
    for (int t = 0; t < 4; ++t) acc[t] = (f32x4){0.f, 0.f, 0.f, 0.f};

    #pragma unroll
    for (int s = 0; s < 2; ++s)
        #pragma unroll
        for (int t = 0; t < 4; ++t)
            acc[t] = __builtin_amdgcn_mfma_f32_16x16x32_bf16(afrag[s], bfrag[s][t], acc[t], 0, 0, 0);

    #pragma unroll
    for (int t = 0; t < 4; ++t)
        #pragma unroll
        for (int p = 0; p < 4; ++p)
            c_lds[(wave * 16 + koct * 4 + p) * 64 + t * 16 + row16] = acc[t][p];
    __syncthreads();

    #pragma unroll
    for (int i = 0; i < 4; ++i) {
        int c = tid + i * 256;
        int r = c >> 4;
        int cq = c & 15;
        f32x4 v = ((const f32x4*)c_lds)[c];
        f32x4 rv = {fmaxf(v.x, 0.f), fmaxf(v.y, 0.f), fmaxf(v.z, 0.f), fmaxf(v.w, 0.f)};
        *(f32x4*)(out + (g0 + r) * OUT_ROW + cq * 4) = rv;
    }
    #pragma unroll
    for (int i = 0; i < 2; ++i) {
        int c = tid + i * 256;
        int r = c >> 3;
        int part = c & 7;
        const float* src = c_lds + r * 64 + part * 8;
        ushort4 lo, hi;
        lo.x = f32_to_bf16_rne(src[0]); lo.y = f32_to_bf16_rne(src[1]);
        lo.z = f32_to_bf16_rne(src[2]); lo.w = f32_to_bf16_rne(src[3]);
        hi.x = f32_to_bf16_rne(src[4]); hi.y = f32_to_bf16_rne(src[5]);
        hi.z = f32_to_bf16_rne(src[6]); hi.w = f32_to_bf16_rne(src[7]);
        unsigned short* dst = Q + (g0 + r) * FIN + part * 8;
        *(ushort4*)(dst) = lo;
        *(ushort4*)(dst + 4) = hi;
    }
}

// ---------------- Kernel 2: right half = relu(mean_src Q_bf16[src]) ----------------
// 2 blocks per node (half-row each), 192 threads x 8 elems = 1536; 4/2/1 edge unroll.

__device__ __forceinline__ void acc_u4(float* a, uint4 v) {
    a[0] += __uint_as_float(v.x << 16); a[1] += __uint_as_float(v.x & 0xffff0000u);
    a[2] += __uint_as_float(v.y << 16); a[3] += __uint_as_float(v.y & 0xffff0000u);
    a[4] += __uint_as_float(v.z << 16); a[5] += __uint_as_float(v.z & 0xffff0000u);
    a[6] += __uint_as_float(v.w << 16); a[7] += __uint_as_float(v.w & 0xffff0000u);
}

__global__ __launch_bounds__(192) void gather_kernel(
    const unsigned short* __restrict__ Q,
    const int* __restrict__ counts,
    const int* __restrict__ bucket,
    float* __restrict__ out) {
    const int n = blockIdx.x >> 1;
    const int half = blockIdx.x & 1;
    const int tid = threadIdx.x;
    const int elem0 = half * 1536 + tid * 8;      // this thread's 8 elems
    const int cnt_true = counts[n];
    const int cnt = cnt_true < CAP ? cnt_true : CAP;
    const int* bk = bucket + n * CAP;

    float acc[8];
    #pragma unroll
    for (int i = 0; i < 8; ++i) acc[i] = 0.f;

    int e = 0;
    for (; e + 4 <= cnt; e += 4) {
        const unsigned short* q0 = Q + (size_t)bk[e]     * NODE_ELEMS + elem0;
        const unsigned short* q1 = Q + (size_t)bk[e + 1] * NODE_ELEMS + elem0;
        const unsigned short* q2 = Q + (size_t)bk[e + 2] * NODE_ELEMS + elem0;
        const unsigned short* q3 = Q + (size_t)bk[e + 3] * NODE_ELEMS + elem0;
        uint4 a0 = *(const uint4*)(q0);
        uint4 a1 = *(const uint4*)(q1);
        uint4 a2 = *(const uint4*)(q2);
        uint4 a3 = *(const uint4*)(q3);
        acc_u4(acc, a0); acc_u4(acc, a1); acc_u4(acc, a2); acc_u4(acc, a3);
    }
    if (e + 2 <= cnt) {
        const unsigned short* q0 = Q + (size_t)bk[e]     * NODE_ELEMS + elem0;
        const unsigned short* q1 = Q + (size_t)bk[e + 1] * NODE_ELEMS + elem0;
        uint4 a0 = *(const uint4*)(q0);
        uint4 a1 = *(const uint4*)(q1);
        acc_u4(acc, a0); acc_u4(acc, a1);
        e += 2;
    }
    if (e < cnt) {
        const unsigned short* q0 = Q + (size_t)bk[e] * NODE_ELEMS + elem0;
        uint4 a0 = *(const uint4*)(q0);
        acc_u4(acc, a0);
    }

    const float inv = 1.0f / (float)(cnt_true > 1 ? cnt_true : 1);
    // elem0 -> row elem0>>6, col elem0&63
    int r = elem0 >> 6, c = elem0 & 63;
    float* p = out + (size_t)n * NODE_OUT + r * OUT_ROW + 64 + c;
    f32x4 v0 = {fmaxf(acc[0] * inv, 0.f), fmaxf(acc[1] * inv, 0.f),
                fmaxf(acc[2] * inv, 0.f), fmaxf(acc[3] * inv, 0.f)};
    f32x4 v1 = {fmaxf(acc[4] * inv, 0.f), fmaxf(acc[5] * inv, 0.f),
                fmaxf(acc[6] * inv, 0.f), fmaxf(acc[7] * inv, 0.f)};
    *(f32x4*)(p)     = v0;
    *(f32x4*)(p + 4) = v1;
}

// ---------------- Fallback path (tiny ws): scan CSR + fused f32 kernel ----------------

__global__ void zero_counts_kernel(int* __restrict__ counts) {
    int i = blockIdx.x * 256 + threadIdx.x;
    if (i < N_NODES) counts[i] = 0;
}

__global__ void hist_kernel(const int* __restrict__ edges_dst, int* __restrict__ counts) {
    int e = blockIdx.x * 256 + threadIdx.x;
    if (e < N_EDGES) atomicAdd(&counts[edges_dst[e]], 1);
}

__global__ void scan_kernel(const int* __restrict__ counts,
                            int* __restrict__ offsets,
                            int* __restrict__ cursor) {
    __shared__ int buf[1024];
    __shared__ int carry_s;
    int tid = threadIdx.x;
    if (tid == 0) carry_s = 0;
    __syncthreads();
    for (int base = 0; base < N_NODES; base += 1024) {
        int i = base + tid;
        int v = (i < N_NODES) ? counts[i] : 0;
        buf[tid] = v;
        __syncthreads();
        int x = v;
        for (int off = 1; off < 1024; off <<= 1) {
            int t = (tid >= off) ? buf[tid - off] : 0;
            __syncthreads();
            x += t;
            buf[tid] = x;
            __syncthreads();
        }
        int c = carry_s;
        if (i < N_NODES) {
            int excl = c + x - v;
            offsets[i] = excl;
            cursor[i] = excl;
        }
        __syncthreads();
        if (tid == 0) carry_s = c + buf[1023];
        __syncthreads();
    }
    if (threadIdx.x == 0) offsets[N_NODES] = carry_s;
}

__global__ void scatter_kernel(const int* __restrict__ edges_dst,
                               const int* __restrict__ edges_src,
                               int* __restrict__ cursor,
                               int* __restrict__ csr_src) {
    int e = blockIdx.x * 256 + threadIdx.x;
    if (e < N_EDGES) {
        int d = edges_dst[e];
        int p = atomicAdd(&cursor[d], 1);
        csr_src[p] = edges_src[e];
    }
}

__global__ __launch_bounds__(256) void fused_kernel(
    const float* __restrict__ feat,
    const float* __restrict__ W,
    const int* __restrict__ offsets,
    const int* __restrict__ csr_src,
    float* __restrict__ out) {
    __shared__ __align__(16) float lds_w[FIN * FOUT];
    __shared__ __align__(16) float lds_t[NODE_ELEMS];

    const int n = blockIdx.x;
    const int tid = threadIdx.x;

    {
        const f32x4* w4 = (const f32x4*)W;
        f32x4* l4 = (f32x4*)lds_w;
        #pragma unroll
        for (int i = 0; i < 4; ++i) l4[tid + i * 256] = w4[tid + i * 256];
    }
    {
        const f32x4* f4 = (const f32x4*)(feat + (size_t)n * NODE_ELEMS);
        f32x4* l4 = (f32x4*)lds_t;
        #pragma unroll
        for (int i = 0; i < 3; ++i) l4[tid + i * 256] = f4[tid + i * 256];
    }
    __syncthreads();

    const int j = tid & 63;
    float wcol[64];
    #pragma unroll
    for (int k = 0; k < 64; ++k) wcol[k] = lds_w[k * 64 + j];

    float* outn = out + (size_t)n * NODE_OUT;

    #pragma unroll
    for (int i = 0; i < 12; ++i) {
        int r = (tid + i * 256) >> 6;
        const f32x4* m4 = (const f32x4*)(lds_t + r * 64);
        float s = 0.f;
        #pragma unroll
        for (int k4 = 0; k4 < 16; ++k4) {
            f32x4 m = m4[k4];
            s += m.x * wcol[4 * k4 + 0] + m.y * wcol[4 * k4 + 1] +
                 m.z * wcol[4 * k4 + 2] + m.w * wcol[4 * k4 + 3];
        }
        outn[r * OUT_ROW + j] = fmaxf(s, 0.f);
    }

    const int e0 = offsets[n], e1 = offsets[n + 1];
    f32x4 acc[3];
    #pragma unroll
    for (int i = 0; i < 3; ++i) acc[i] = (f32x4){0.f, 0.f, 0.f, 0.f};
    for (int e = e0; e < e1; ++e) {
        int src = csr_src[e];
        const f32x4* f4 = (const f32x4*)(feat + (size_t)src * NODE_ELEMS);
        #pragma unroll
        for (int i = 0; i < 3; ++i) acc[i] += f4[tid + i * 256];
    }
    const float inv = 1.0f / (float)((e1 - e0) > 1 ? (e1 - e0) : 1);

    __syncthreads();
    {
        f32x4* l4 = (f32x4*)lds_t;
        #pragma unroll
        for (int i = 0; i < 3; ++i) l4[tid + i * 256] = acc[i] * inv;
    }
    __syncthreads();

    #pragma unroll
    for (int i = 0; i < 12; ++i) {
        int r = (tid + i * 256) >> 6;
        const f32x4* m4 = (const f32x4*)(lds_t + r * 64);
        float s = 0.f;
        #pragma unroll
        for (int k4 = 0; k4 < 16; ++k4) {
            f32x4 m = m4[k4];
            s += m.x * wcol[4 * k4 + 0] + m.y * wcol[4 * k4 + 1] +
                 m.z * wcol[4 * k4 + 2] + m.w * wcol[4 * k4 + 3];
        }
        outn[r * OUT_ROW + 64 + j] = fmaxf(s, 0.f);
    }
}

// ---------------- launch ----------------

extern "C" void kernel_launch(void* const* d_in, const int* in_sizes, int n_in,
                              void* d_out, int out_size, void* d_ws, size_t ws_size,
                              hipStream_t stream) {
    const float* feat = (const float*)d_in[0];
    const float* W    = (const float*)d_in[1];
    const int* edst   = (const int*)d_in[2];
    const int* esrc   = (const int*)d_in[3];
    float* out = (float*)d_out;

    // bucket-path layout
    int* counts  = (int*)d_ws;                               // 5000 ints (pad to 20480 B)
    int* bucket  = (int*)((char*)d_ws + 20480);              // 5000*64 ints = 1.28 MB
    const size_t wt_off = 20480 + (size_t)N_NODES * CAP * 4; // 1,300,480
    unsigned short* Wt = (unsigned short*)((char*)d_ws + wt_off);   // 8 KB
    const size_t q_off = wt_off + 8192;                      // 1,308,672 (256-aligned)
    unsigned short* Q = (unsigned short*)((char*)d_ws + q_off);
    const size_t q_bytes = (size_t)N_NODES * NODE_ELEMS * 2; // 30.72 MB

    if (ws_size >= q_off + q_bytes) {
        hipMemsetAsync(counts, 0, N_NODES * sizeof(int), stream);
        bucket_wt_kernel<<<EDGE_BLOCKS + 1, 256, 0, stream>>>(edst, esrc, W, counts, bucket, Wt);
        mfma_matmul_kernel<<<M_ROWS / 64, 256, 0, stream>>>(feat, Wt, out, Q);
        gather_kernel<<<N_NODES * 2, 192, 0, stream>>>(Q, counts, bucket, out);
    } else {
        // fallback: packed CSR + fused f32 kernel (tiny ws)
        int* offsets = counts + N_NODES;
        int* cursor  = offsets + N_NODES + 1;
        int* csr_src = cursor + N_NODES;
        zero_counts_kernel<<<(N_NODES + 255) / 256, 256, 0, stream>>>(counts);
        hist_kernel<<<(N_EDGES + 255) / 256, 256, 0, stream>>>(edst, counts);
        scan_kernel<<<1, 1024, 0, stream>>>(counts, offsets, cursor);
        scatter_kernel<<<(N_EDGES + 255) / 256, 256, 0, stream>>>(edst, esrc, cursor, csr_src);
        fused_kernel<<<N_NODES, 256, 0, stream>>>(feat, W, offsets, csr_src, out);
    }
}